// Round 1
// baseline (120.216 us; speedup 1.0000x reference)
//
#include <hip/hip_runtime.h>
#include <hip/hip_bf16.h>

#define B_ 32
#define N_ 1024
#define F_ 128
#define D_ 128
// dk = 128^-0.5 / 1024
#define DK_CONST 8.631674575031098e-05f

typedef unsigned short u16;
typedef __attribute__((ext_vector_type(8))) short short8;
typedef __attribute__((ext_vector_type(4))) float floatx4;

__device__ __forceinline__ u16 f2b(float x) {
    union { float f; unsigned u; } v; v.f = x;
    unsigned u = v.u;
    return (u16)((u + 0x7FFFu + ((u >> 16) & 1u)) >> 16);
}
__device__ __forceinline__ float b2f(u16 h) {
    union { unsigned u; float f; } v; v.u = ((unsigned)h) << 16;
    return v.f;
}

// ---------------- Kernel P: Mt[g][f] = bf16( sum_d Wk[g,d]*Wq[f,d] ) ----------------
__global__ __launch_bounds__(128) void precompute_mt(const float* __restrict__ Wq,
                                                     const float* __restrict__ Wk,
                                                     u16* __restrict__ Mt) {
    __shared__ float wk[128];
    __shared__ float wq[128][129];
    int g = blockIdx.x, t = threadIdx.x;
    wk[t] = Wk[g * 128 + t];
    for (int r = 0; r < 128; ++r) wq[r][t] = Wq[r * 128 + t];  // coalesced
    __syncthreads();
    float s = 0.f;
    for (int d = 0; d < 128; ++d) s += wk[d] * wq[t][d];
    Mt[g * 128 + t] = f2b(s);
}

// ---------------- Kernel A: quad_i = aq_i^T M aq_i  (bf16 MFMA) + colsum partials ----
__global__ __launch_bounds__(256) void quad_kernel(const float* __restrict__ aq,
                                                   const u16* __restrict__ Mt,
                                                   float* __restrict__ quadOut,
                                                   float* __restrict__ colsumPart) {
    __shared__ __align__(16) u16 aqT[128][136];   // [m][k] bf16, padded
    __shared__ __align__(16) u16 mtT[128][136];   // [n=g][k=f] bf16 (B^T layout)
    __shared__ float qpart[2][128];
    __shared__ float cspart[256][4];

    int t = threadIdx.x;
    int tile = blockIdx.x;                         // 256 tiles of 128 atoms
    const float* aqBlk = aq + (size_t)tile * 128 * 128;

    // stage aq tile (f32 -> bf16) + accumulate f32 column-sum partials
    float cs0 = 0.f, cs1 = 0.f, cs2 = 0.f, cs3 = 0.f;
    for (int j = 0; j < 16; ++j) {
        int idx = t + 256 * j;                     // float4 index, 4096 total
        int row = idx >> 5;
        int c4  = idx & 31;                        // == t & 31 (fixed per thread)
        float4 v = ((const float4*)aqBlk)[idx];
        cs0 += v.x; cs1 += v.y; cs2 += v.z; cs3 += v.w;
        ushort4 bb;
        bb.x = f2b(v.x); bb.y = f2b(v.y); bb.z = f2b(v.z); bb.w = f2b(v.w);
        *((ushort4*)&aqT[row][c4 * 4]) = bb;
    }
    cspart[t][0] = cs0; cspart[t][1] = cs1; cspart[t][2] = cs2; cspart[t][3] = cs3;

    // stage Mt (bf16, 128x128)
    for (int j = 0; j < 16; ++j) {
        int idx = t + 256 * j;                     // ushort4 index, 4096 total
        int row = idx >> 5;
        int c4  = idx & 31;
        ushort4 mv = ((const ushort4*)Mt)[idx];
        *((ushort4*)&mtT[row][c4 * 4]) = mv;
    }
    __syncthreads();

    // reduce colsum partials -> global (8 contributors per column)
    if (t < 128) {
        int c4i = t >> 2, comp = t & 3;
        float s = 0.f;
        for (int h = 0; h < 8; ++h) s += cspart[h * 32 + c4i][comp];
        colsumPart[tile * 128 + t] = s;
    }

    // MFMA GEMM: T = AqTile[128x128] * M[128x128]; each wave does 64x64
    int w = t >> 6;
    int lane = t & 63;
    int wr = (w >> 1) * 64;
    int wc = (w & 1) * 64;
    int lm = lane & 15;
    int lq = lane >> 4;

    floatx4 acc[4][4];
    for (int i = 0; i < 4; ++i)
        for (int j = 0; j < 4; ++j)
            acc[i][j] = (floatx4){0.f, 0.f, 0.f, 0.f};

    for (int ks = 0; ks < 4; ++ks) {
        int k0 = ks * 32 + lq * 8;
        short8 afr[4], bfr[4];
        for (int i = 0; i < 4; ++i) {
            afr[i] = *(const short8*)&aqT[wr + i * 16 + lm][k0];
            bfr[i] = *(const short8*)&mtT[wc + i * 16 + lm][k0];
        }
        for (int i = 0; i < 4; ++i)
            for (int j = 0; j < 4; ++j)
                acc[i][j] = __builtin_amdgcn_mfma_f32_16x16x32_bf16(afr[i], bfr[j], acc[i][j], 0, 0, 0);
    }

    // epilogue: quad_row = sum_col T[row,col] * aq_bf16[row,col]
    for (int mi = 0; mi < 4; ++mi) {
        for (int r = 0; r < 4; ++r) {
            int row = wr + mi * 16 + lq * 4 + r;
            float s = 0.f;
            for (int nj = 0; nj < 4; ++nj) {
                int col = wc + nj * 16 + lm;
                s += acc[mi][nj][r] * b2f(aqT[row][col]);
            }
            for (int d = 1; d < 16; d <<= 1) s += __shfl_xor(s, d);
            if (lm == 0) qpart[w & 1][row] = s;
        }
    }
    __syncthreads();
    if (t < 128) quadOut[tile * 128 + t] = qpart[0][t] + qpart[1][t];
}

// ---------------- Kernel B: per-batch Ksum, U, C ----------------
__global__ __launch_bounds__(128) void batch_kernel(const float* __restrict__ colsumPart,
                                                    const float* __restrict__ Wq,
                                                    const float* __restrict__ Wk,
                                                    const float* __restrict__ bq,
                                                    const float* __restrict__ bk,
                                                    float* __restrict__ U,
                                                    float* __restrict__ Cb) {
    __shared__ float cs[128], ksm[128], red[128];
    int b = blockIdx.x, t = threadIdx.x;
    float s = 0.f;
    for (int h = 0; h < 8; ++h) s += colsumPart[(b * 8 + h) * 128 + t];
    cs[t] = s;
    __syncthreads();
    // Ksum[d] = colsum . Wk[:,d] + N*bk[d]
    float kd = 0.f;
    for (int f = 0; f < 128; ++f) kd += cs[f] * Wk[f * 128 + t];
    kd += (float)N_ * bk[t];
    ksm[t] = kd;
    __syncthreads();
    // C_b = bq . (Ksum - bk)
    red[t] = bq[t] * (ksm[t] - bk[t]);
    __syncthreads();
    for (int st = 64; st > 0; st >>= 1) {
        if (t < st) red[t] += red[t + st];
        __syncthreads();
    }
    if (t == 0) Cb[b] = red[0];
    // U[f] = sum_d Wq[f,d]*(Ksum[d]-bk[d]) - sum_d Wk[f,d]*bq[d]
    float u = 0.f;
    for (int d = 0; d < 128; ++d) {
        u += Wq[t * 128 + d] * (ksm[d] - bk[d]) - Wk[t * 128 + d] * bq[d];
    }
    U[b * 128 + t] = u;
}

// ---------------- Kernel C: agg_i = mask_i * dk * (aq_i.U + C - quad_i) -------------
__global__ __launch_bounds__(256) void dot_kernel(const float* __restrict__ aq,
                                                  const float* __restrict__ mask,
                                                  const float* __restrict__ U,
                                                  const float* __restrict__ Cb,
                                                  const float* __restrict__ quad,
                                                  float* __restrict__ agg) {
    int b = blockIdx.x, blk = blockIdx.y;          // grid (32, 16), 64 atoms/block
    int t = threadIdx.x;
    int part = t & 31, h = t >> 5;
    const float4* aq4 = (const float4*)(aq + ((size_t)b * N_ + blk * 64) * 128);
    const float4* U4 = (const float4*)(U + b * 128);
    float4 uv = U4[part];
    float cb = Cb[b];
    for (int j = 0; j < 8; ++j) {
        int row = j * 8 + h;
        float4 a = aq4[row * 32 + part];
        float s = a.x * uv.x + a.y * uv.y + a.z * uv.z + a.w * uv.w;
        for (int d = 1; d < 32; d <<= 1) s += __shfl_xor(s, d);
        if (part == 0) {
            int atom = b * N_ + blk * 64 + row;
            agg[atom] = mask[atom] * DK_CONST * (s + cb - quad[atom]);
        }
    }
}

// ---------------- Kernel D: normalize + mask + softmax over atoms -> attn -----------
__global__ __launch_bounds__(256) void softmax_kernel(const float* __restrict__ agg,
                                                      const float* __restrict__ mask,
                                                      float* __restrict__ attnOut) {
    __shared__ float red[256];
    int b = blockIdx.x, t = threadIdx.x;
    float a[4], m[4];
    float ss = 0.f;
    for (int j = 0; j < 4; ++j) {
        int i = b * N_ + j * 256 + t;
        a[j] = agg[i]; m[j] = mask[i];
        ss += a[j] * a[j];
    }
    red[t] = ss;
    __syncthreads();
    for (int st = 128; st > 0; st >>= 1) {
        if (t < st) red[t] += red[t + st];
        __syncthreads();
    }
    float invn = 1.0f / sqrtf(red[0]);
    __syncthreads();
    float z[4], mx = -3.0e38f;
    for (int j = 0; j < 4; ++j) {
        z[j] = (m[j] > 0.5f) ? a[j] * invn : -1.0e9f;
        mx = fmaxf(mx, z[j]);
    }
    red[t] = mx;
    __syncthreads();
    for (int st = 128; st > 0; st >>= 1) {
        if (t < st) red[t] = fmaxf(red[t], red[t + st]);
        __syncthreads();
    }
    mx = red[0];
    __syncthreads();
    float e[4], es = 0.f;
    for (int j = 0; j < 4; ++j) {
        e[j] = expf(z[j] - mx);
        es += e[j];
    }
    red[t] = es;
    __syncthreads();
    for (int st = 128; st > 0; st >>= 1) {
        if (t < st) red[t] += red[t + st];
        __syncthreads();
    }
    float inv = 1.0f / red[0];
    for (int j = 0; j < 4; ++j)
        attnOut[b * N_ + j * 256 + t] = e[j] * inv;
}

// ---------------- Kernel E: wsum_b[f] = sum_i (attn*mask)_i aq[b,i,f] (partials) -----
__global__ __launch_bounds__(256) void wsum_kernel(const float* __restrict__ aq,
                                                   const float* __restrict__ mask,
                                                   const float* __restrict__ attn,
                                                   float* __restrict__ wsumPart,
                                                   float* __restrict__ wmassPart) {
    __shared__ float acc2[2][128];
    __shared__ float wm[2];
    int b = blockIdx.x, sblk = blockIdx.y;          // grid (32, 8), 128 rows/block
    int t = threadIdx.x;
    int f = t & 127, h = t >> 7;
    float acc = 0.f, wacc = 0.f;
    for (int r = h; r < 128; r += 2) {
        int atom = b * N_ + sblk * 128 + r;
        float wgt = attn[atom] * mask[atom];
        acc += wgt * aq[(size_t)atom * 128 + f];
        wacc += wgt;
    }
    acc2[h][f] = acc;
    if (f == 0) wm[h] = wacc;
    __syncthreads();
    if (t < 128) wsumPart[(b * 8 + sblk) * 128 + t] = acc2[0][t] + acc2[1][t];
    if (t == 0) wmassPart[b * 8 + sblk] = wm[0] + wm[1];
}

// ---------------- Kernel F: context[b,d] = wsum_b . Wv[:,d] + wmass*bv[d] ------------
__global__ __launch_bounds__(128) void context_kernel(const float* __restrict__ wsumPart,
                                                      const float* __restrict__ wmassPart,
                                                      const float* __restrict__ Wv,
                                                      const float* __restrict__ bv,
                                                      float* __restrict__ ctxOut) {
    __shared__ float wsl[128];
    __shared__ float wmass_s;
    int b = blockIdx.x, t = threadIdx.x;
    float s = 0.f;
    for (int h = 0; h < 8; ++h) s += wsumPart[(b * 8 + h) * 128 + t];
    wsl[t] = s;
    if (t == 0) {
        float wmv = 0.f;
        for (int h = 0; h < 8; ++h) wmv += wmassPart[b * 8 + h];
        wmass_s = wmv;
    }
    __syncthreads();
    float c = 0.f;
    for (int f = 0; f < 128; ++f) c += wsl[f] * Wv[f * 128 + t];
    c += wmass_s * bv[t];
    ctxOut[b * 128 + t] = c;
}

extern "C" void kernel_launch(void* const* d_in, const int* in_sizes, int n_in,
                              void* d_out, int out_size, void* d_ws, size_t ws_size,
                              hipStream_t stream) {
    const float* aq   = (const float*)d_in[0];   // [B,N,F]
    const float* mask = (const float*)d_in[1];   // [B,N,1]
    const float* Wq   = (const float*)d_in[2];
    const float* bq   = (const float*)d_in[3];
    const float* Wk   = (const float*)d_in[4];
    const float* bk   = (const float*)d_in[5];
    const float* Wv   = (const float*)d_in[6];
    const float* bv   = (const float*)d_in[7];

    float* out_attn = (float*)d_out;             // [B,N,1] = 32768
    float* out_ctx  = out_attn + B_ * N_;        // [B,D]   = 4096

    float* wsf        = (float*)d_ws;
    float* quad       = wsf;                     // 32768
    float* colsumPart = wsf + 32768;             // 32768  (256 tiles x 128)
    float* U          = wsf + 65536;             // 4096
    float* Cb         = wsf + 69632;             // 32
    float* agg        = wsf + 69664;             // 32768
    float* wsumPart   = wsf + 102432;            // 32768  (32x8x128)
    float* wmassPart  = wsf + 135200;            // 256
    u16*   Mt         = (u16*)(wsf + 135456);    // 128x128 bf16

    precompute_mt<<<128, 128, 0, stream>>>(Wq, Wk, Mt);
    quad_kernel<<<256, 256, 0, stream>>>(aq, Mt, quad, colsumPart);
    batch_kernel<<<32, 128, 0, stream>>>(colsumPart, Wq, Wk, bq, bk, U, Cb);
    dot_kernel<<<dim3(32, 16), 256, 0, stream>>>(aq, mask, U, Cb, quad, agg);
    softmax_kernel<<<32, 256, 0, stream>>>(agg, mask, out_attn);
    wsum_kernel<<<dim3(32, 8), 256, 0, stream>>>(aq, mask, out_attn, wsumPart, wmassPart);
    context_kernel<<<32, 128, 0, stream>>>(wsumPart, wmassPart, Wv, bv, out_ctx);
}

// Round 2
// 102.315 us; speedup vs baseline: 1.1750x; 1.1750x over previous
//
#include <hip/hip_runtime.h>

#define B_ 32
#define N_ 1024
#define F_ 128
#define D_ 128
// dk = 128^-0.5 / 1024
#define DK_CONST 8.631674575031098e-05f
#define NM1 1023.0f

typedef unsigned short u16;
typedef __attribute__((ext_vector_type(8))) short short8;
typedef __attribute__((ext_vector_type(4))) float floatx4;

__device__ __forceinline__ u16 f2b(float x) {
    union { float f; unsigned u; } v; v.f = x;
    unsigned u = v.u;
    return (u16)((u + 0x7FFFu + ((u >> 16) & 1u)) >> 16);
}
__device__ __forceinline__ float b2f(u16 h) {
    union { unsigned u; float f; } v; v.u = ((unsigned)h) << 16;
    return v.f;
}

// ============ K1: colsum partials (blocks 0..255) + Mt = (Wk Wq^T) bf16 (blocks 256..319) ============
__global__ __launch_bounds__(256) void k1_colsum_mt(const float* __restrict__ aq,
                                                    const float* __restrict__ Wq,
                                                    const float* __restrict__ Wk,
                                                    float* __restrict__ colsumPart,
                                                    u16* __restrict__ Mt) {
    __shared__ float cspart[256][4];
    __shared__ float wq[128][129];
    __shared__ float wk2[2][128];
    int t = threadIdx.x;
    if (blockIdx.x < 256) {
        int tile = blockIdx.x;
        const float4* aq4 = (const float4*)(aq + (size_t)tile * 128 * 128);
        float c0 = 0.f, c1 = 0.f, c2 = 0.f, c3 = 0.f;
        for (int j = 0; j < 16; ++j) {
            float4 v = aq4[t + 256 * j];
            c0 += v.x; c1 += v.y; c2 += v.z; c3 += v.w;
        }
        cspart[t][0] = c0; cspart[t][1] = c1; cspart[t][2] = c2; cspart[t][3] = c3;
        __syncthreads();
        if (t < 128) {
            int c4i = t >> 2, comp = t & 3;
            float s = 0.f;
            for (int h = 0; h < 8; ++h) s += cspart[h * 32 + c4i][comp];
            colsumPart[tile * 128 + t] = s;
        }
    } else {
        int mb = blockIdx.x - 256;           // 0..63, rows 2mb, 2mb+1 of Mt
        int h = t >> 7, f = t & 127;
        for (int j = 0; j < 64; ++j) {
            int idx = t + 256 * j;
            wq[idx >> 7][idx & 127] = Wq[idx];
        }
        wk2[h][f] = Wk[(mb * 2 + h) * 128 + f];
        __syncthreads();
        float s = 0.f;
        for (int d = 0; d < 128; ++d) s += wk2[h][d] * wq[f][d];
        Mt[(mb * 2 + h) * 128 + f] = f2b(s);
    }
}

// ============ K2: per-batch S, const_b; global wc = (N-1)Wq·bk - Wk·bq ============
__global__ __launch_bounds__(128) void k2_batch(const float* __restrict__ colsumPart,
                                                const float* __restrict__ Wq,
                                                const float* __restrict__ Wk,
                                                const float* __restrict__ bq,
                                                const float* __restrict__ bk,
                                                float* __restrict__ Sb,
                                                float* __restrict__ Cb,
                                                float* __restrict__ wc) {
    __shared__ float w[128][129];
    __shared__ float red[128];
    int b = blockIdx.x, t = threadIdx.x;
    float s = 0.f;
    for (int h = 0; h < 8; ++h) s += colsumPart[(b * 8 + h) * 128 + t];
    Sb[b * 128 + t] = s;
    float bqv = bq[t], bkv = bk[t];
    red[t] = fabsf(bqv) + fabsf(bkv);
    __syncthreads();
    for (int st = 64; st > 0; st >>= 1) { if (t < st) red[t] += red[t + st]; __syncthreads(); }
    float nb = red[0];
    __syncthreads();
    float w1 = 0.f, w2 = 0.f, bqbk = 0.f;
    if (nb != 0.f) {                                  // block-uniform branch
        for (int r = 0; r < 128; ++r) w[r][t] = Wq[r * 128 + t];
        __syncthreads();
        for (int d = 0; d < 128; ++d) w1 += w[t][d] * bk[d];
        __syncthreads();
        for (int r = 0; r < 128; ++r) w[r][t] = Wk[r * 128 + t];
        __syncthreads();
        for (int d = 0; d < 128; ++d) w2 += w[t][d] * bq[d];
        red[t] = bqv * bkv;
        __syncthreads();
        for (int st = 64; st > 0; st >>= 1) { if (t < st) red[t] += red[t + st]; __syncthreads(); }
        bqbk = red[0];
        __syncthreads();
    }
    if (b == 0) wc[t] = NM1 * w1 - w2;
    red[t] = s * w2;
    __syncthreads();
    for (int st = 64; st > 0; st >>= 1) { if (t < st) red[t] += red[t + st]; __syncthreads(); }
    if (t == 0) Cb[b] = red[0] + NM1 * bqbk;
}

// ============ K3: T = AqTile*M (MFMA); agg_i = mask*dk*(T_i·(S-aq_i) + aq_i·wc + C_b) ============
__global__ __launch_bounds__(256) void k3_agg(const float* __restrict__ aq,
                                              const u16* __restrict__ Mt,
                                              const float* __restrict__ mask,
                                              const float* __restrict__ Sb,
                                              const float* __restrict__ Cb,
                                              const float* __restrict__ wc,
                                              float* __restrict__ agg) {
    __shared__ __align__(16) u16 aqT[128][136];   // [m][k] bf16, padded
    __shared__ __align__(16) u16 mtT[128][136];   // [n=g][k=f] bf16 (B^T layout)
    __shared__ float qpart[2][128];
    __shared__ float Sl[128], wcl[128];

    int t = threadIdx.x;
    int tile = blockIdx.x;                         // 256 tiles of 128 atoms
    int b = tile >> 3;
    const float* aqBlk = aq + (size_t)tile * 128 * 128;

    if (t < 128) { Sl[t] = Sb[b * 128 + t]; wcl[t] = wc[t]; }

    for (int j = 0; j < 16; ++j) {
        int idx = t + 256 * j;
        int row = idx >> 5;
        int c4  = idx & 31;
        float4 v = ((const float4*)aqBlk)[idx];
        ushort4 bb;
        bb.x = f2b(v.x); bb.y = f2b(v.y); bb.z = f2b(v.z); bb.w = f2b(v.w);
        *((ushort4*)&aqT[row][c4 * 4]) = bb;
    }
    for (int j = 0; j < 16; ++j) {
        int idx = t + 256 * j;
        int row = idx >> 5;
        int c4  = idx & 31;
        ushort4 mv = ((const ushort4*)Mt)[idx];
        *((ushort4*)&mtT[row][c4 * 4]) = mv;
    }
    __syncthreads();

    int w = t >> 6;
    int lane = t & 63;
    int wr   = (w >> 1) * 64;
    int wcol = (w & 1) * 64;
    int lm = lane & 15;
    int lq = lane >> 4;

    floatx4 acc[4][4];
    for (int i = 0; i < 4; ++i)
        for (int j = 0; j < 4; ++j)
            acc[i][j] = (floatx4){0.f, 0.f, 0.f, 0.f};

    for (int ks = 0; ks < 4; ++ks) {
        int k0 = ks * 32 + lq * 8;
        short8 afr[4], bfr[4];
        for (int i = 0; i < 4; ++i) {
            afr[i] = *(const short8*)&aqT[wr + i * 16 + lm][k0];
            bfr[i] = *(const short8*)&mtT[wcol + i * 16 + lm][k0];
        }
        for (int i = 0; i < 4; ++i)
            for (int j = 0; j < 4; ++j)
                acc[i][j] = __builtin_amdgcn_mfma_f32_16x16x32_bf16(afr[i], bfr[j], acc[i][j], 0, 0, 0);
    }

    // epilogue: s_row = sum_col T*(S[col]-aq) + aq*wc[col]
    for (int mi = 0; mi < 4; ++mi) {
        for (int r = 0; r < 4; ++r) {
            int row = wr + mi * 16 + lq * 4 + r;
            float s = 0.f;
            for (int nj = 0; nj < 4; ++nj) {
                int col = wcol + nj * 16 + lm;
                float av = b2f(aqT[row][col]);
                float T  = acc[mi][nj][r];
                s += T * (Sl[col] - av) + av * wcl[col];
            }
            for (int d = 1; d < 16; d <<= 1) s += __shfl_xor(s, d);
            if (lm == 0) qpart[w & 1][row] = s;
        }
    }
    __syncthreads();
    if (t < 128) {
        int atom = tile * 128 + t;
        agg[atom] = mask[atom] * DK_CONST * (qpart[0][t] + qpart[1][t] + Cb[b]);
    }
}

// ============ K4: normalize + mask + softmax over atoms -> attn; zero ctx ============
__global__ __launch_bounds__(256) void k4_softmax(const float* __restrict__ agg,
                                                  const float* __restrict__ mask,
                                                  float* __restrict__ attnOut,
                                                  float* __restrict__ ctxOut) {
    __shared__ float red[256];
    int b = blockIdx.x, t = threadIdx.x;
    if (t < 128) ctxOut[b * 128 + t] = 0.f;
    float a[4], m[4];
    float ss = 0.f;
    for (int j = 0; j < 4; ++j) {
        int i = b * N_ + j * 256 + t;
        a[j] = agg[i]; m[j] = mask[i];
        ss += a[j] * a[j];
    }
    red[t] = ss;
    __syncthreads();
    for (int st = 128; st > 0; st >>= 1) {
        if (t < st) red[t] += red[t + st];
        __syncthreads();
    }
    float invn = 1.0f / sqrtf(red[0]);
    __syncthreads();
    float z[4], mx = -3.0e38f;
    for (int j = 0; j < 4; ++j) {
        z[j] = (m[j] > 0.5f) ? a[j] * invn : -1.0e9f;
        mx = fmaxf(mx, z[j]);
    }
    red[t] = mx;
    __syncthreads();
    for (int st = 128; st > 0; st >>= 1) {
        if (t < st) red[t] = fmaxf(red[t], red[t + st]);
        __syncthreads();
    }
    mx = red[0];
    __syncthreads();
    float e[4], es = 0.f;
    for (int j = 0; j < 4; ++j) {
        e[j] = expf(z[j] - mx);
        es += e[j];
    }
    red[t] = es;
    __syncthreads();
    for (int st = 128; st > 0; st >>= 1) {
        if (t < st) red[t] += red[t + st];
        __syncthreads();
    }
    float inv = 1.0f / red[0];
    for (int j = 0; j < 4; ++j)
        attnOut[b * N_ + j * 256 + t] = e[j] * inv;
}

// ============ K5: weighted sum over 128 atoms, project by Wv, atomicAdd into ctx ============
__global__ __launch_bounds__(256) void k5_ctx(const float* __restrict__ aq,
                                              const float* __restrict__ mask,
                                              const float* __restrict__ attn,
                                              const float* __restrict__ Wv,
                                              const float* __restrict__ bv,
                                              float* __restrict__ ctx) {
    __shared__ float wl[128];
    __shared__ float accs[4][128];
    __shared__ float p[128];
    __shared__ float wmass_s;
    int b = blockIdx.x, sblk = blockIdx.y, t = threadIdx.x;
    int base = b * N_ + sblk * 128;
    if (t < 128) wl[t] = attn[base + t] * mask[base + t];
    __syncthreads();
    int f2i = t & 63, h = t >> 6;
    const float2* aq2 = (const float2*)(aq + (size_t)base * 128);
    float2 acc; acc.x = 0.f; acc.y = 0.f;
    for (int r = h; r < 128; r += 4) {
        float2 v = aq2[r * 64 + f2i];
        float wgt = wl[r];
        acc.x += wgt * v.x; acc.y += wgt * v.y;
    }
    *((float2*)&accs[h][2 * f2i]) = acc;
    if (t < 64) {
        float wm = wl[t] + wl[t + 64];
        for (int d = 1; d < 64; d <<= 1) wm += __shfl_xor(wm, d);
        if (t == 0) wmass_s = wm;
    }
    __syncthreads();
    if (t < 128) p[t] = accs[0][t] + accs[1][t] + accs[2][t] + accs[3][t];
    __syncthreads();
    if (t < 128) {
        float c = 0.f;
        for (int f = 0; f < 128; ++f) c += p[f] * Wv[f * 128 + t];
        c += wmass_s * bv[t];
        atomicAdd(&ctx[b * 128 + t], c);
    }
}

extern "C" void kernel_launch(void* const* d_in, const int* in_sizes, int n_in,
                              void* d_out, int out_size, void* d_ws, size_t ws_size,
                              hipStream_t stream) {
    const float* aq   = (const float*)d_in[0];   // [B,N,F]
    const float* mask = (const float*)d_in[1];   // [B,N,1]
    const float* Wq   = (const float*)d_in[2];
    const float* bq   = (const float*)d_in[3];
    const float* Wk   = (const float*)d_in[4];
    const float* bk   = (const float*)d_in[5];
    const float* Wv   = (const float*)d_in[6];
    const float* bv   = (const float*)d_in[7];

    float* out_attn = (float*)d_out;             // [B,N,1] = 32768
    float* out_ctx  = out_attn + B_ * N_;        // [B,D]   = 4096

    float* wsf        = (float*)d_ws;
    float* colsumPart = wsf;                     // 32768
    float* Sb         = wsf + 32768;             // 4096
    float* Cb         = wsf + 36864;             // 32
    float* wc         = wsf + 36896;             // 128
    float* agg        = wsf + 37024;             // 32768
    u16*   Mt         = (u16*)(wsf + 69792);     // 128x128 bf16

    k1_colsum_mt<<<320, 256, 0, stream>>>(aq, Wq, Wk, colsumPart, Mt);
    k2_batch<<<32, 128, 0, stream>>>(colsumPart, Wq, Wk, bq, bk, Sb, Cb, wc);
    k3_agg<<<256, 256, 0, stream>>>(aq, Mt, mask, Sb, Cb, wc, agg);
    k4_softmax<<<32, 256, 0, stream>>>(agg, mask, out_attn, out_ctx);
    k5_ctx<<<dim3(32, 8), 256, 0, stream>>>(aq, mask, out_attn, Wv, bv, out_ctx);
}